// Round 4
// baseline (366.185 us; speedup 1.0000x reference)
//
#include <hip/hip_runtime.h>
#include <hip/hip_bf16.h>
#include <stdint.h>

#define E_NUM 16
#define T_NUM 8192
#define H_DIM 1024
#define I_DIM 4096
#define MPE   512   // tokens per expert

typedef __attribute__((ext_vector_type(8))) short short8;
typedef __attribute__((ext_vector_type(4))) float f32x4;
using bf16 = __hip_bfloat16;

typedef const __attribute__((address_space(1))) void GLV;
typedef __attribute__((address_space(3))) void LDSV;

__device__ __forceinline__ uint32_t pack2_bf16(float a, float b) {
  union { float f; uint32_t u; } ua, ub;
  ua.f = a; ub.f = b;
  uint32_t x = ua.u + (0x7FFFu + ((ua.u >> 16) & 1u));
  uint32_t y = ub.u + (0x7FFFu + ((ub.u >> 16) & 1u));
  return (x >> 16) | (y & 0xFFFF0000u);
}

// 8 f32 (two float4) -> uint4 of 8 bf16 (RNE, v_cvt_pk_bf16_f32)
__device__ __forceinline__ uint4 cvt8u(float4 a, float4 b) {
  union { uint4 u; __hip_bfloat162 h[4]; } r;
  r.h[0] = __float22bfloat162_rn({a.x, a.y});
  r.h[1] = __float22bfloat162_rn({a.z, a.w});
  r.h[2] = __float22bfloat162_rn({b.x, b.y});
  r.h[3] = __float22bfloat162_rn({b.z, b.w});
  return r.u;
}

// ---------------- gather + cast: xp[r] = bf16(hs[perm[r]]) ----------------
__global__ __launch_bounds__(256)
void gather_cast_kernel(const float* __restrict__ hs, const int* __restrict__ perm,
                        uint32_t* __restrict__ xp) {
  const int r = blockIdx.x;
  const int t = threadIdx.x;
  const int src = perm[r];
  float4 v = ((const float4*)(hs + (size_t)src * H_DIM))[t];
  uint2 o;
  o.x = pack2_bf16(v.x, v.y);
  o.y = pack2_bf16(v.z, v.w);
  ((uint2*)(xp + (size_t)r * (H_DIM / 2)))[t] = o;
}

// ---------------- grouped GEMM, fine-phase pipeline ----------------
// C = A(bf16,[E][512][K]) * B(f32,[E][N][K])^T.  BM=256, BN=128, BK=64.
// 512 thr = 8 waves (4M x 2N), per-wave 64x64 (4x4 frags), acc 64 VGPR.
// LDS: both tiles bf16, [rows][64] (128-B rows) with chunk^(row&7) XOR swizzle
// (R2-verified 0-conflict).  A: global_load_lds w/ pre-swizzled source.
// B: fp32->reg (phase 0) -> vmcnt(4) -> cvt_pk -> swizzled ds_write (phase 1).
// 2 phases/K-tile: {ds_read frags | stage-issue | barrier | lgkm0 | 16 MFMA | barrier}.
template<bool EPI1, int N, int K, int LOG_NBN>
__global__ __launch_bounds__(512, 2)
void moe_gemm_kernel(const bf16* __restrict__ A, const float* __restrict__ Bw,
                     const float* __restrict__ bias, bf16* __restrict__ Hout,
                     float* __restrict__ Oout, const int* __restrict__ perm) {
  constexpr int NK = K / 64;
  __shared__ bf16 As[2][256 * 64];   // 32 KB each
  __shared__ bf16 Bs[2][128 * 64];   // 16 KB each

  // bijective chunked XCD swizzle (m204); nwg % 8 == 0
  const int nwg = gridDim.x, qx = nwg >> 3, orig = blockIdx.x;
  const int wg = (orig & 7) * qx + (orig >> 3);
  const int bm = wg & 1;
  const int bn = (wg >> 1) & ((1 << LOG_NBN) - 1);
  const int e  = wg >> (1 + LOG_NBN);

  const int tid = threadIdx.x;
  const int l = tid & 63;
  const int w = tid >> 6;
  const int wr = w >> 1, wc = w & 1;       // 4 M-waves x 2 N-waves
  const int fr = l & 15, fq = l >> 4;
  const int rx = fr & 7;

  const bf16*  Ae = A  + ((size_t)e * MPE + (size_t)bm * 256) * K;
  const float* Be = Bw + ((size_t)e * N + (size_t)bn * 128) * K;

  // A staging: op i covers LDS chunks [i*512 + tid]; chunk L -> row L>>3, phys p=L&7,
  // logical c = p ^ (row&7)  (row = i*64 + (tid>>3); i*64 % 8 == 0 so swizzle const over i)
  const int ar = tid >> 3;
  const bf16* Asrc = Ae + (size_t)ar * K + (((tid & 7) ^ (ar & 7)) << 3);

  // B staging: row br = tid>>2 (128 rows), fp32 segment bs = tid&3 (64 B = 16 elems)
  const int br = tid >> 2, bs = tid & 3;
  const float* Bsrc = Be + (size_t)br * K + bs * 16;
  const int bwo0 = br * 64 + ((((bs << 1))     ^ (br & 7)) << 3);
  const int bwo1 = br * 64 + ((((bs << 1) | 1) ^ (br & 7)) << 3);

  // frag read element offsets (row*64 + swizzled_chunk*8)
  const int aro = (wr * 64 + fr) * 64;     // + m*1024 + chunk*8
  const int bro = (wc * 64 + fr) * 64;     // + n*1024 + chunk*8
  const int ch0 = ((0 * 4 + fq) ^ rx) << 3;   // kstep 0 chunk byte-offset/2
  const int ch1 = ((1 * 4 + fq) ^ rx) << 3;

  f32x4 acc[4][4];
#pragma unroll
  for (int m = 0; m < 4; ++m)
#pragma unroll
    for (int n = 0; n < 4; ++n) acc[m][n] = (f32x4){0.f, 0.f, 0.f, 0.f};

  float4 breg[4];

#define ISSUE_B(kt)                                                          \
  {                                                                          \
    const float* g = Bsrc + (kt) * 64;                                       \
    breg[0] = *(const float4*)(g);                                           \
    breg[1] = *(const float4*)(g + 4);                                       \
    breg[2] = *(const float4*)(g + 8);                                       \
    breg[3] = *(const float4*)(g + 12);                                      \
  }

#define ISSUE_A(buf, kt)                                                     \
  {                                                                          \
    _Pragma("unroll")                                                        \
    for (int i = 0; i < 4; ++i)                                              \
      __builtin_amdgcn_global_load_lds((GLV*)(Asrc + (size_t)i * 64 * K + (kt) * 64), \
                                       (LDSV*)&As[buf][(i * 512 + tid) * 8], 16, 0, 0); \
  }

#define CVT_WRITE_B(buf)                                                     \
  {                                                                          \
    *(uint4*)&Bs[buf][bwo0] = cvt8u(breg[0], breg[1]);                       \
    *(uint4*)&Bs[buf][bwo1] = cvt8u(breg[2], breg[3]);                       \
  }

  // ---- prologue: fully stage tile 0 into buffer 0
  ISSUE_B(0);
  ISSUE_A(0, 0);
  asm volatile("s_waitcnt vmcnt(4)" ::: "memory");   // B regs landed (A still out)
  __builtin_amdgcn_sched_barrier(0);
  CVT_WRITE_B(0);
  asm volatile("s_waitcnt vmcnt(0) lgkmcnt(0)" ::: "memory");
  __builtin_amdgcn_sched_barrier(0);
  __builtin_amdgcn_s_barrier();

  for (int t = 0; t < NK; ++t) {
    const int cur = t & 1, nxt = cur ^ 1;
    const bool more = (t + 1) < NK;

    // ---------- phase 0 (kstep 0) ----------
    short8 a8[4], b8[4];
#pragma unroll
    for (int m = 0; m < 4; ++m)
      a8[m] = *(const short8*)&As[cur][aro + m * 1024 + ch0];
#pragma unroll
    for (int n = 0; n < 4; ++n)
      b8[n] = *(const short8*)&Bs[cur][bro + n * 1024 + ch0];
    if (more) ISSUE_B(t + 1);
    __builtin_amdgcn_s_barrier();
    asm volatile("s_waitcnt lgkmcnt(0)" ::: "memory");
    __builtin_amdgcn_sched_barrier(0);
    __builtin_amdgcn_s_setprio(1);
#pragma unroll
    for (int m = 0; m < 4; ++m)
#pragma unroll
      for (int n = 0; n < 4; ++n)
        acc[m][n] = __builtin_amdgcn_mfma_f32_16x16x32_bf16(a8[m], b8[n], acc[m][n], 0, 0, 0);
    __builtin_amdgcn_s_setprio(0);
    __builtin_amdgcn_s_barrier();

    // ---------- phase 1 (kstep 1) ----------
#pragma unroll
    for (int m = 0; m < 4; ++m)
      a8[m] = *(const short8*)&As[cur][aro + m * 1024 + ch1];
#pragma unroll
    for (int n = 0; n < 4; ++n)
      b8[n] = *(const short8*)&Bs[cur][bro + n * 1024 + ch1];
    if (more) {
      ISSUE_A(nxt, t + 1);
      asm volatile("s_waitcnt vmcnt(4)" ::: "memory");   // B(t+1) regs landed
      __builtin_amdgcn_sched_barrier(0);
      CVT_WRITE_B(nxt);
    }
    __builtin_amdgcn_s_barrier();
    asm volatile("s_waitcnt lgkmcnt(0)" ::: "memory");
    __builtin_amdgcn_sched_barrier(0);
    __builtin_amdgcn_s_setprio(1);
#pragma unroll
    for (int m = 0; m < 4; ++m)
#pragma unroll
      for (int n = 0; n < 4; ++n)
        acc[m][n] = __builtin_amdgcn_mfma_f32_16x16x32_bf16(a8[m], b8[n], acc[m][n], 0, 0, 0);
    __builtin_amdgcn_s_setprio(0);
    __builtin_amdgcn_sched_barrier(0);
    // publish buffer nxt: A gload_lds done (issued >=1 phase ago -> cheap wait),
    // ds_writes retired; then barrier
    asm volatile("s_waitcnt vmcnt(0) lgkmcnt(0)" ::: "memory");
    __builtin_amdgcn_sched_barrier(0);
    __builtin_amdgcn_s_barrier();
  }

  // ---- epilogue
  float bv[4];
#pragma unroll
  for (int n = 0; n < 4; ++n)
    bv[n] = bias[(size_t)e * N + bn * 128 + wc * 64 + n * 16 + fr];

  if (EPI1) {
    bf16* He = Hout + (size_t)e * MPE * N;
#pragma unroll
    for (int m = 0; m < 4; ++m) {
#pragma unroll
      for (int j = 0; j < 4; ++j) {
        const int row = bm * 256 + wr * 64 + m * 16 + fq * 4 + j;
#pragma unroll
        for (int n = 0; n < 4; ++n) {
          const int col = bn * 128 + wc * 64 + n * 16 + fr;
          float x = acc[m][n][j] + bv[n];
          float g = 0.5f * x * (1.0f + erff(x * 0.70710678118654752f));
          He[(size_t)row * N + col] = __float2bfloat16(g);
        }
      }
    }
  } else {
#pragma unroll
    for (int m = 0; m < 4; ++m) {
#pragma unroll
      for (int j = 0; j < 4; ++j) {
        const int grow = e * MPE + bm * 256 + wr * 64 + m * 16 + fq * 4 + j;
        const int drow = perm[grow];
        float* orow = Oout + (size_t)drow * N;
#pragma unroll
        for (int n = 0; n < 4; ++n) {
          const int col = bn * 128 + wc * 64 + n * 16 + fr;
          orow[col] = acc[m][n][j] + bv[n];
        }
      }
    }
  }
#undef ISSUE_B
#undef ISSUE_A
#undef CVT_WRITE_B
}

// ---------------- residual + LayerNorm (in place on out) ----------------
__global__ __launch_bounds__(256)
void ln_resid_kernel(float* __restrict__ out, const float* __restrict__ hs,
                     const float* __restrict__ gamma, const float* __restrict__ beta) {
  const int r = blockIdx.x;
  const int t = threadIdx.x;
  float4 o = ((const float4*)(out + (size_t)r * H_DIM))[t];
  float4 h = ((const float4*)(hs  + (size_t)r * H_DIM))[t];
  float v0 = o.x + h.x, v1 = o.y + h.y, v2 = o.z + h.z, v3 = o.w + h.w;
  float s  = v0 + v1 + v2 + v3;
  float sq = v0 * v0 + v1 * v1 + v2 * v2 + v3 * v3;
#pragma unroll
  for (int off = 32; off > 0; off >>= 1) {
    s  += __shfl_down(s, off);
    sq += __shfl_down(sq, off);
  }
  __shared__ float ss[4], ssq[4];
  const int wv = t >> 6;
  if ((t & 63) == 0) { ss[wv] = s; ssq[wv] = sq; }
  __syncthreads();
  s  = ss[0] + ss[1] + ss[2] + ss[3];
  sq = ssq[0] + ssq[1] + ssq[2] + ssq[3];
  const float mu  = s * (1.0f / (float)H_DIM);
  const float var = sq * (1.0f / (float)H_DIM) - mu * mu;
  const float rs  = rsqrtf(var + 1e-12f);
  float4 g = ((const float4*)gamma)[t];
  float4 b = ((const float4*)beta)[t];
  float4 rr;
  rr.x = (v0 - mu) * rs * g.x + b.x;
  rr.y = (v1 - mu) * rs * g.y + b.y;
  rr.z = (v2 - mu) * rs * g.z + b.z;
  rr.w = (v3 - mu) * rs * g.w + b.w;
  ((float4*)(out + (size_t)r * H_DIM))[t] = rr;
}

extern "C" void kernel_launch(void* const* d_in, const int* in_sizes, int n_in,
                              void* d_out, int out_size, void* d_ws, size_t ws_size,
                              hipStream_t stream) {
  const float* hs    = (const float*)d_in[0];
  const int*   perm  = (const int*)d_in[1];
  const float* w1    = (const float*)d_in[2];
  const float* b1    = (const float*)d_in[3];
  const float* w2    = (const float*)d_in[4];
  const float* b2    = (const float*)d_in[5];
  const float* gamma = (const float*)d_in[6];
  const float* beta  = (const float*)d_in[7];
  float* out = (float*)d_out;

  bf16* xp   = (bf16*)d_ws;                                              // 16 MB
  bf16* hbuf = (bf16*)((char*)d_ws + (size_t)T_NUM * H_DIM * sizeof(bf16)); // 64 MB

  gather_cast_kernel<<<T_NUM, 256, 0, stream>>>(hs, perm, (uint32_t*)xp);

  // GEMM1: nwg = 2 * (4096/128) * 16 = 1024
  moe_gemm_kernel<true, I_DIM, H_DIM, 5><<<1024, 512, 0, stream>>>(xp, w1, b1, hbuf, nullptr, nullptr);

  // GEMM2: nwg = 2 * (1024/128) * 16 = 256
  moe_gemm_kernel<false, H_DIM, I_DIM, 3><<<256, 512, 0, stream>>>(hbuf, w2, b2, nullptr, out, perm);

  ln_resid_kernel<<<T_NUM, 256, 0, stream>>>(out, hs, gamma, beta);
}